// Round 5
// baseline (201.929 us; speedup 1.0000x reference)
//
#include <hip/hip_runtime.h>

// NetVLAD: N=16, C=1024, P=1024, K=32.
// Pipeline: detect -> k_norm (x-hat bf16 in [c][p] AND [p][c] + w bf16)
//           -> k_attn (MFMA logits+softmax) -> k_vlad (MFMA) -> factors -> out.
#define NB   16
#define CC   1024
#define PP   1024
#define KK   32
#define EPSF 1e-12f

typedef __attribute__((ext_vector_type(8))) short  bf16x8;
typedef __attribute__((ext_vector_type(4))) float  f32x4;
typedef unsigned short us;

__device__ __forceinline__ float bf2f(us u) {
    union { unsigned int i; float f; } v; v.i = ((unsigned int)u) << 16; return v.f;
}
__device__ __forceinline__ us f2bf(float f) {
    union { float f; unsigned int i; } v; v.f = f;
    return (us)((v.i + 0x7fffu + ((v.i >> 16) & 1u)) >> 16);  // RNE
}

template <typename T> struct IO;
template <> struct IO<float> {
    static __device__ __forceinline__ float  ld (const float* p) { return *p; }
    static __device__ __forceinline__ float4 ld4(const float* p) { return *(const float4*)p; }
};
template <> struct IO<us> {
    static __device__ __forceinline__ float  ld (const us* p) { return bf2f(*p); }
    static __device__ __forceinline__ float4 ld4(const us* p) {
        const ushort4 u = *(const ushort4*)p;
        return make_float4(bf2f(u.x), bf2f(u.y), bf2f(u.z), bf2f(u.w));
    }
};

// ---------------------------------------------------------------------------
// K0: dtype detect (fp32 read as bf16 shows impossible exponents).
// ---------------------------------------------------------------------------
__global__ __launch_bounds__(256) void k_detect(const us* __restrict__ xu,
                                                int* __restrict__ flag) {
    __shared__ int s;
    const int t = threadIdx.x;
    if (t == 0) s = 0;
    __syncthreads();
    int bad = 0;
    for (int i = t; i < 4096; i += 256)
        if (((xu[i] >> 7) & 0xFFu) > 0x9Fu) bad = 1;
    if (bad) atomicOr(&s, 1);
    __syncthreads();
    if (t == 0) flag[0] = s;
}

// ---------------------------------------------------------------------------
// K1 (k_norm): blocks 0..511: per (n, 32px): sumsq -> rnorm; write
// xhat[c][p] bf16 + xhatT[p][c] bf16. blocks 512..527: convert W -> bf16.
// ---------------------------------------------------------------------------
template <typename T>
__device__ __forceinline__ void norm_body(const T* __restrict__ x,
                                          const T* __restrict__ w,
                                          us* __restrict__ xhat,
                                          us* __restrict__ xhatT,
                                          us* __restrict__ what) {
    const int b = blockIdx.x, t = threadIdx.x;
    if (b >= NB * 32) {               // W conversion
        const int base = (b - NB * 32) * 2048 + t * 8;
        const float4 v0 = IO<T>::ld4(w + base);
        const float4 v1 = IO<T>::ld4(w + base + 4);
        ushort4 u0, u1;
        u0.x = f2bf(v0.x); u0.y = f2bf(v0.y); u0.z = f2bf(v0.z); u0.w = f2bf(v0.w);
        u1.x = f2bf(v1.x); u1.y = f2bf(v1.y); u1.z = f2bf(v1.z); u1.w = f2bf(v1.w);
        *(ushort4*)&what[base]     = u0;
        *(ushort4*)&what[base + 4] = u1;
        return;
    }
    __shared__ float red[32 * 33];
    __shared__ float rn[32];
    const int n = b >> 5, pbase = (b & 31) * 32;
    const int a = t & 7, crow = t >> 3;      // a: px-quad, crow: c-row 0..31
    const int pxg = 4 * a;
    const size_t xb = (size_t)n * CC * PP + pbase;
    // pass 1: sumsq over c per px
    float s0 = 0.f, s1 = 0.f, s2 = 0.f, s3 = 0.f;
    for (int i = 0; i < 32; ++i) {
        const int c = crow + 32 * i;
        const float4 v = IO<T>::ld4(x + xb + (size_t)c * PP + pxg);
        s0 += v.x * v.x; s1 += v.y * v.y; s2 += v.z * v.z; s3 += v.w * v.w;
    }
    red[crow * 33 + pxg + 0] = s0;
    red[crow * 33 + pxg + 1] = s1;
    red[crow * 33 + pxg + 2] = s2;
    red[crow * 33 + pxg + 3] = s3;
    __syncthreads();
    if (t < 32) {
        float s = 0.f;
        #pragma unroll
        for (int g = 0; g < 32; ++g) s += red[g * 33 + t];
        rn[t] = 1.0f / fmaxf(sqrtf(s), EPSF);
    }
    __syncthreads();
    // pass 2a: xhat[c][p] (re-read, L2-hot)
    const float r0 = rn[pxg], r1 = rn[pxg + 1], r2 = rn[pxg + 2], r3 = rn[pxg + 3];
    for (int i = 0; i < 32; ++i) {
        const int c = crow + 32 * i;
        const float4 v = IO<T>::ld4(x + xb + (size_t)c * PP + pxg);
        ushort4 u;
        u.x = f2bf(v.x * r0); u.y = f2bf(v.y * r1);
        u.z = f2bf(v.z * r2); u.w = f2bf(v.w * r3);
        *(ushort4*)&xhat[((size_t)n * CC + c) * PP + pbase + pxg] = u;
    }
    // pass 2b: xhatT[p][c]
    const int px = t & 31, cq = t >> 5;      // cq 0..7
    const float rpx = rn[px];
    const size_t tb = ((size_t)n * PP + pbase + px) * CC;
    for (int i = 0; i < 32; ++i) {
        const int c4 = 4 * (cq + 8 * i);
        const float v0 = IO<T>::ld(x + xb + (size_t)(c4 + 0) * PP + px);
        const float v1 = IO<T>::ld(x + xb + (size_t)(c4 + 1) * PP + px);
        const float v2 = IO<T>::ld(x + xb + (size_t)(c4 + 2) * PP + px);
        const float v3 = IO<T>::ld(x + xb + (size_t)(c4 + 3) * PP + px);
        ushort4 u;
        u.x = f2bf(v0 * rpx); u.y = f2bf(v1 * rpx);
        u.z = f2bf(v2 * rpx); u.w = f2bf(v3 * rpx);
        *(ushort4*)&xhatT[tb + c4] = u;
    }
}
__global__ __launch_bounds__(256) void k_norm(const void* __restrict__ x,
                                              const void* __restrict__ w,
                                              const int* __restrict__ flag,
                                              us* __restrict__ xhat,
                                              us* __restrict__ xhatT,
                                              us* __restrict__ what) {
    if (*flag) norm_body<float>((const float*)x, (const float*)w, xhat, xhatT, what);
    else       norm_body<us>((const us*)x, (const us*)w, xhat, xhatT, what);
}

// ---------------------------------------------------------------------------
// K2 (k_attn): per (n, 32px): logits = xhatT @ whatT (M=32px, N=32k, K=1024c)
// via MFMA; softmax over k; write attn bf16 + asum. W-fragments direct from
// global (L2-hot); xhatT staged to LDS via uint4 (conflict-free phases).
// grid 512, block 256 (4 waves: mt x ntk).
// ---------------------------------------------------------------------------
__global__ __launch_bounds__(256) void k_attn(const us* __restrict__ xhatT,
                                              const us* __restrict__ what,
                                              us* __restrict__ attn_g,
                                              float* __restrict__ asum) {
    __shared__ __align__(16) us xt[32 * 136];   // [px][c-chunk] pad 136
    __shared__ float lg[32 * 33];
    __shared__ float inv_lds[32];
    const int b = blockIdx.x, t = threadIdx.x;
    const int n = b >> 5, pbase = (b & 31) * 32;
    const int lane = t & 63, wv = t >> 6;       // 4 waves
    const int quad = lane >> 4, l15 = lane & 15;
    const int mt = wv >> 1, ntk = wv & 1;

    f32x4 acc = {0.f, 0.f, 0.f, 0.f};
    const size_t xtb = ((size_t)n * PP + pbase) * CC;

    for (int ch = 0; ch < 8; ++ch) {
        const int c0 = ch * 128;
        __syncthreads();
        // stage 32px x 128c: 256 thr x 2 uint4
        #pragma unroll
        for (int s = 0; s < 2; ++s) {
            const int idx = t + 256 * s;
            const int px = idx >> 4, unit = idx & 15;
            const uint4 u = *(const uint4*)&xhatT[xtb + (size_t)px * CC + c0 + unit * 8];
            *(uint4*)&xt[px * 136 + unit * 8] = u;
        }
        __syncthreads();
        #pragma unroll
        for (int ks = 0; ks < 4; ++ks) {
            const bf16x8 av = *(const bf16x8*)&xt[(mt * 16 + l15) * 136 + ks * 32 + quad * 8];
            const bf16x8 bv = *(const bf16x8*)&what[(ntk * 16 + l15) * CC + c0 + ks * 32 + quad * 8];
            acc = __builtin_amdgcn_mfma_f32_16x16x32_bf16(av, bv, acc, 0, 0, 0);
        }
    }
    __syncthreads();
    // D: row = px-local = quad*4+reg (+mt*16), col = k-local = l15 (+ntk*16)
    #pragma unroll
    for (int reg = 0; reg < 4; ++reg) {
        const int px = mt * 16 + quad * 4 + reg;
        lg[px * 33 + ntk * 16 + l15] = acc[reg];
    }
    __syncthreads();
    if (t < 32) {
        float m = -1e30f;
        #pragma unroll
        for (int k = 0; k < KK; ++k) m = fmaxf(m, lg[t * 33 + k]);
        float s = 0.f;
        #pragma unroll
        for (int k = 0; k < KK; ++k) {
            const float e = expf(lg[t * 33 + k] - m);
            lg[t * 33 + k] = e;
            s += e;
        }
        inv_lds[t] = 1.0f / s;
    }
    __syncthreads();
    // attn write: thread: k = t>>3, 4 px; 256 thr covers 32k x 32px? -> use
    // k = t>>3 (32), ps = (t&7)*4
    {
        const int k = t >> 3, ps = (t & 7) * 4;
        ushort4 u;
        float sum = 0.f;
        #pragma unroll
        for (int j = 0; j < 4; ++j) {
            const int px = ps + j;
            const us e = f2bf(lg[px * 33 + k] * inv_lds[px]);
            ((us*)&u)[j] = e;
            sum += bf2f(e);
        }
        *(ushort4*)&attn_g[((size_t)n * KK + k) * PP + pbase + ps] = u;
        sum += __shfl_down(sum, 1, 64);
        sum += __shfl_down(sum, 2, 64);
        sum += __shfl_down(sum, 4, 64);
        if ((t & 7) == 0) atomicAdd(&asum[n * KK + k], sum);
    }
}

// ---------------------------------------------------------------------------
// K3 (k_vlad): per (n, 32c): vlad = attn @ xhat^T (M=32k, N=32c, K=1024p).
// A-fragments direct from attn (L2-resident); B = xhat staged uint4->LDS.
// Epilogue: -asum*cent, store fp32, ssq atomics. grid 512, block 256.
// ---------------------------------------------------------------------------
template <typename T>
__device__ __forceinline__ void vlad_body(const us* __restrict__ xhat,
                                          const us* __restrict__ attn_g,
                                          const T* __restrict__ cent,
                                          const float* __restrict__ asum,
                                          float* __restrict__ vlad,
                                          float* __restrict__ ssqnk) {
    __shared__ __align__(16) us xc[32 * 136];   // [c-local][p-chunk] pad 136
    __shared__ float asum_lds[32];
    const int b = blockIdx.x, t = threadIdx.x;
    const int n = b >> 5, cb = (b & 31) * 32;
    const int lane = t & 63, wv = t >> 6;
    const int quad = lane >> 4, l15 = lane & 15;
    const int mtk = wv >> 1, ntc = wv & 1;

    if (t < 32) asum_lds[t] = asum[n * KK + t];

    f32x4 acc = {0.f, 0.f, 0.f, 0.f};
    const size_t xb = ((size_t)n * CC + cb) * PP;
    const size_t ab = ((size_t)n * KK + mtk * 16 + l15) * PP;

    for (int ch = 0; ch < 8; ++ch) {
        const int p0 = ch * 128;
        __syncthreads();
        #pragma unroll
        for (int s = 0; s < 2; ++s) {
            const int idx = t + 256 * s;
            const int ci = idx >> 4, unit = idx & 15;
            const uint4 u = *(const uint4*)&xhat[xb + (size_t)ci * PP + p0 + unit * 8];
            *(uint4*)&xc[ci * 136 + unit * 8] = u;
        }
        __syncthreads();
        #pragma unroll
        for (int ks = 0; ks < 4; ++ks) {
            const bf16x8 av = *(const bf16x8*)&attn_g[ab + p0 + ks * 32 + quad * 8];
            const bf16x8 bv = *(const bf16x8*)&xc[(ntc * 16 + l15) * 136 + ks * 32 + quad * 8];
            acc = __builtin_amdgcn_mfma_f32_16x16x32_bf16(av, bv, acc, 0, 0, 0);
        }
    }
    // D: row = k-local = quad*4+reg (+mtk*16), col = c-local = l15 (+ntc*16)
    const int cg = cb + ntc * 16 + l15;
    #pragma unroll
    for (int reg = 0; reg < 4; ++reg) {
        const int k = mtk * 16 + quad * 4 + reg;
        const float A = asum_lds[k];
        const float v = acc[reg] - A * IO<T>::ld(&cent[k * CC + cg]);
        vlad[((size_t)n * KK + k) * CC + cg] = v;
        float s = v * v;
        s += __shfl_xor(s, 1, 64);
        s += __shfl_xor(s, 2, 64);
        s += __shfl_xor(s, 4, 64);
        s += __shfl_xor(s, 8, 64);
        if (l15 == 0) atomicAdd(&ssqnk[n * KK + k], s);
    }
}
__global__ __launch_bounds__(256) void k_vlad(const us* __restrict__ xhat,
                                              const us* __restrict__ attn_g,
                                              const void* __restrict__ cent,
                                              const int* __restrict__ flag,
                                              const float* __restrict__ asum,
                                              float* __restrict__ vlad,
                                              float* __restrict__ ssqnk) {
    if (*flag) vlad_body<float>(xhat, attn_g, (const float*)cent, asum, vlad, ssqnk);
    else       vlad_body<us>(xhat, attn_g, (const us*)cent, asum, vlad, ssqnk);
}

// ---------------------------------------------------------------------------
// K4: per (n,k) intra rnorm; per n global rnorm (sum_k ssq_k * r_k^2).
// ---------------------------------------------------------------------------
__global__ __launch_bounds__(64) void k_factors(const float* __restrict__ ssqnk,
                                                float* __restrict__ rintra,
                                                float* __restrict__ rglob) {
    const int n = blockIdx.x, t = threadIdx.x;
    const float s = (t < KK) ? ssqnk[n * KK + t] : 0.f;
    const float r = 1.0f / fmaxf(sqrtf(s), EPSF);
    if (t < KK) rintra[n * KK + t] = r;
    float g = s * r * r;
    for (int off = 32; off > 0; off >>= 1) g += __shfl_down(g, off, 64);
    if (t == 0) rglob[n] = 1.0f / fmaxf(sqrtf(g), EPSF);
}

// ---------------------------------------------------------------------------
// K5: out = vlad * rintra * rglob. grid N*K, 256 thr (float4 per thread).
// ---------------------------------------------------------------------------
__global__ __launch_bounds__(256) void k_out(const float* __restrict__ vlad,
                                             const float* __restrict__ rintra,
                                             const float* __restrict__ rglob,
                                             const int* __restrict__ flag,
                                             void* __restrict__ out) {
    const int b = blockIdx.x, t = threadIdx.x;
    const float f = rintra[b] * rglob[b >> 5];
    const float4 v = ((const float4*)(vlad + (size_t)b * CC))[t];
    if (*flag) {
        float4 o; o.x = v.x * f; o.y = v.y * f; o.z = v.z * f; o.w = v.w * f;
        ((float4*)((float*)out + (size_t)b * CC))[t] = o;
    } else {
        ushort4 u;
        u.x = f2bf(v.x * f); u.y = f2bf(v.y * f);
        u.z = f2bf(v.z * f); u.w = f2bf(v.w * f);
        ((ushort4*)((us*)out + (size_t)b * CC))[t] = u;
    }
}

extern "C" void kernel_launch(void* const* d_in, const int* in_sizes, int n_in,
                              void* d_out, int out_size, void* d_ws, size_t ws_size,
                              hipStream_t stream) {
    const void* x    = d_in[0];
    const void* w    = d_in[1];
    const void* cent = d_in[2];

    float* ws     = (float*)d_ws;
    float* vlad   = ws;                       // 524288 f
    float* asum   = vlad + 524288;            // 512 f
    float* ssqnk  = asum + 512;               // 512 f
    float* rintra = ssqnk + 512;              // 512 f
    float* rglob  = rintra + 512;             // 16 f
    int*   flag   = (int*)(rglob + 16);       // 4 i
    us* attn_g = (us*)(flag + 4);             // 524288 us
    us* xhat   = attn_g + 524288;             // 16777216 us
    us* xhatT  = xhat + 16777216;             // 16777216 us
    us* what   = xhatT + 16777216;            // 32768 us

    hipMemsetAsync(asum, 0, 2 * NB * KK * sizeof(float), stream);  // asum+ssqnk

    k_detect<<<1, 256, 0, stream>>>((const us*)x, flag);
    k_norm<<<NB * 32 + 16, 256, 0, stream>>>(x, w, flag, xhat, xhatT, what);
    k_attn<<<NB * 32, 256, 0, stream>>>(xhatT, what, attn_g, asum);
    k_vlad<<<NB * 32, 256, 0, stream>>>(xhat, attn_g, cent, flag, asum, vlad, ssqnk);
    k_factors<<<NB, 64, 0, stream>>>(ssqnk, rintra, rglob);
    k_out<<<NB * KK, 256, 0, stream>>>(vlad, rintra, rglob, flag, d_out);
}

// Round 6
// 172.381 us; speedup vs baseline: 1.1714x; 1.1714x over previous
//
#include <hip/hip_runtime.h>

// NetVLAD: N=16, C=1024, P=1024, K=32.
// detect+Wcvt -> k_attn (fused rnorm+logits MFMA+softmax, writes a~=a*rn bf16,
// asum fp32, xbf=bf16(x)) -> k_vlad (pure-copy MFMA) -> factors -> out.
#define NB   16
#define CC   1024
#define PP   1024
#define KK   32
#define EPSF 1e-12f

typedef __attribute__((ext_vector_type(8))) short  bf16x8;
typedef __attribute__((ext_vector_type(4))) float  f32x4;
typedef unsigned short us;

__device__ __forceinline__ float bf2f(us u) {
    union { unsigned int i; float f; } v; v.i = ((unsigned int)u) << 16; return v.f;
}
__device__ __forceinline__ us f2bf(float f) {
    union { float f; unsigned int i; } v; v.f = f;
    return (us)((v.i + 0x7fffu + ((v.i >> 16) & 1u)) >> 16);  // RNE
}

template <typename T> struct IO;
template <> struct IO<float> {
    static __device__ __forceinline__ float  ld (const float* p) { return *p; }
    static __device__ __forceinline__ float4 ld4(const float* p) { return *(const float4*)p; }
};
template <> struct IO<us> {
    static __device__ __forceinline__ float  ld (const us* p) { return bf2f(*p); }
    static __device__ __forceinline__ float4 ld4(const us* p) {
        const ushort4 u = *(const ushort4*)p;
        return make_float4(bf2f(u.x), bf2f(u.y), bf2f(u.z), bf2f(u.w));
    }
};

// ---------------------------------------------------------------------------
// K0 (k_prep): grid 16. Each block independently detects dtype (fp32 read as
// bf16 shows impossible exponents in first 4096 ushorts), block 0 publishes
// the flag, and every block converts its W slice to bf16 (copy if already).
// ---------------------------------------------------------------------------
__global__ __launch_bounds__(256) void k_prep(const us* __restrict__ xu,
                                              const void* __restrict__ w,
                                              int* __restrict__ flag,
                                              us* __restrict__ wbf) {
    __shared__ int s;
    const int b = blockIdx.x, t = threadIdx.x;
    if (t == 0) s = 0;
    __syncthreads();
    int bad = 0;
    for (int i = t; i < 4096; i += 256)
        if (((xu[i] >> 7) & 0xFFu) > 0x9Fu) bad = 1;
    if (bad) atomicOr(&s, 1);
    __syncthreads();
    const int f = s;
    if (b == 0 && t == 0) flag[0] = f;
    const int base = b * 2048 + t * 8;
    if (f) {
        const float* wf = (const float*)w;
        const float4 v0 = *(const float4*)(wf + base);
        const float4 v1 = *(const float4*)(wf + base + 4);
        ushort4 u0, u1;
        u0.x = f2bf(v0.x); u0.y = f2bf(v0.y); u0.z = f2bf(v0.z); u0.w = f2bf(v0.w);
        u1.x = f2bf(v1.x); u1.y = f2bf(v1.y); u1.z = f2bf(v1.z); u1.w = f2bf(v1.w);
        *(ushort4*)&wbf[base]     = u0;
        *(ushort4*)&wbf[base + 4] = u1;
    } else {
        *(uint4*)&wbf[base] = *(const uint4*)((const us*)w + base);
    }
}

// ---------------------------------------------------------------------------
// K1 (k_attn): per (n, 32px): register-prefetch pipeline over 8 c-chunks:
// load x fp32 -> sumsq + bf16 cvt -> LDS transpose scatter (+xbf writeback)
// -> MFMA logits (M=32px,N=32k,K=1024c, W-frags direct from global wbf).
// Epilogue: rnorm, softmax, write a~=a*rn bf16 + asum fp32.
// grid 512, block 256 (4 waves: mt x ntk).
// ---------------------------------------------------------------------------
template <typename T, bool WRITE_XBF>
__device__ __forceinline__ void attn_body(const T* __restrict__ x,
                                          const us* __restrict__ wbf,
                                          us* __restrict__ xbf,
                                          us* __restrict__ attn_g,
                                          float* __restrict__ asum) {
    __shared__ __align__(16) us xt[32 * 136];   // [px][c-chunk] pad 136
    __shared__ float red[32 * 33];
    __shared__ float lg[32 * 33];
    __shared__ float inv_lds[32];
    __shared__ float rn_lds[32];
    const int b = blockIdx.x, t = threadIdx.x;
    const int n = b >> 5, pbase = (b & 31) * 32;
    const int lane = t & 63, wv = t >> 6;
    const int quad = lane >> 4, l15 = lane & 15;
    const int mt = wv >> 1, ntk = wv & 1;
    const int a = t & 7, crow = t >> 3, pxg = 4 * a;
    const size_t xb = (size_t)n * CC * PP + pbase;

    float ss0 = 0.f, ss1 = 0.f, ss2 = 0.f, ss3 = 0.f;
    f32x4 acc = {0.f, 0.f, 0.f, 0.f};

    // prefetch chunk 0
    float4 xr[4];
    #pragma unroll
    for (int ps = 0; ps < 4; ++ps)
        xr[ps] = IO<T>::ld4(x + xb + (size_t)(crow + 32 * ps) * PP + pxg);

    for (int ch = 0; ch < 8; ++ch) {
        const int c0 = ch * 128;
        __syncthreads();
        // consume regs: sumsq + cvt + scatter (+ xbf store)
        #pragma unroll
        for (int ps = 0; ps < 4; ++ps) {
            const float4 v = xr[ps];
            ss0 += v.x * v.x; ss1 += v.y * v.y; ss2 += v.z * v.z; ss3 += v.w * v.w;
            ushort4 u;
            u.x = f2bf(v.x); u.y = f2bf(v.y); u.z = f2bf(v.z); u.w = f2bf(v.w);
            const int cl = crow + 32 * ps;
            xt[(pxg + 0) * 136 + cl] = u.x;
            xt[(pxg + 1) * 136 + cl] = u.y;
            xt[(pxg + 2) * 136 + cl] = u.z;
            xt[(pxg + 3) * 136 + cl] = u.w;
            if (WRITE_XBF)
                *(ushort4*)&xbf[(size_t)(n * CC + c0 + cl) * PP + pbase + pxg] = u;
        }
        __syncthreads();
        // prefetch next chunk while MFMA runs
        if (ch < 7) {
            const int c0n = c0 + 128;
            #pragma unroll
            for (int ps = 0; ps < 4; ++ps)
                xr[ps] = IO<T>::ld4(x + xb + (size_t)(c0n + crow + 32 * ps) * PP + pxg);
        }
        #pragma unroll
        for (int ks = 0; ks < 4; ++ks) {
            const bf16x8 av = *(const bf16x8*)&xt[(mt * 16 + l15) * 136 + ks * 32 + quad * 8];
            const bf16x8 bv = *(const bf16x8*)&wbf[(ntk * 16 + l15) * CC + c0 + ks * 32 + quad * 8];
            acc = __builtin_amdgcn_mfma_f32_16x16x32_bf16(av, bv, acc, 0, 0, 0);
        }
    }
    // rnorm
    red[crow * 33 + pxg + 0] = ss0;
    red[crow * 33 + pxg + 1] = ss1;
    red[crow * 33 + pxg + 2] = ss2;
    red[crow * 33 + pxg + 3] = ss3;
    __syncthreads();
    if (t < 32) {
        float s = 0.f;
        #pragma unroll
        for (int g = 0; g < 32; ++g) s += red[g * 33 + t];
        rn_lds[t] = 1.0f / fmaxf(sqrtf(s), EPSF);
    }
    __syncthreads();
    // logits = acc * rn ;  D: row(px)=quad*4+reg (+mt*16), col(k)=l15 (+ntk*16)
    #pragma unroll
    for (int reg = 0; reg < 4; ++reg) {
        const int px = mt * 16 + quad * 4 + reg;
        lg[px * 33 + ntk * 16 + l15] = acc[reg] * rn_lds[px];
    }
    __syncthreads();
    if (t < 32) {
        float m = -1e30f;
        #pragma unroll
        for (int k = 0; k < KK; ++k) m = fmaxf(m, lg[t * 33 + k]);
        float s = 0.f;
        #pragma unroll
        for (int k = 0; k < KK; ++k) {
            const float e = expf(lg[t * 33 + k] - m);
            lg[t * 33 + k] = e;
            s += e;
        }
        inv_lds[t] = 1.0f / s;
    }
    __syncthreads();
    // write a~ = a*rn (bf16) + asum (fp32, pre-rounding)
    {
        const int k = t >> 3, ps2 = (t & 7) * 4;
        ushort4 u;
        float sum = 0.f;
        #pragma unroll
        for (int j = 0; j < 4; ++j) {
            const int px = ps2 + j;
            const float e = lg[px * 33 + k] * inv_lds[px];   // a (fp32)
            sum += e;
            ((us*)&u)[j] = f2bf(e * rn_lds[px]);             // a~ bf16
        }
        *(ushort4*)&attn_g[((size_t)n * KK + k) * PP + pbase + ps2] = u;
        sum += __shfl_down(sum, 1, 64);
        sum += __shfl_down(sum, 2, 64);
        sum += __shfl_down(sum, 4, 64);
        if ((t & 7) == 0) atomicAdd(&asum[n * KK + k], sum);
    }
}
__global__ __launch_bounds__(256) void k_attn(const void* __restrict__ x,
                                              const us* __restrict__ wbf,
                                              const int* __restrict__ flag,
                                              us* __restrict__ xbf,
                                              us* __restrict__ attn_g,
                                              float* __restrict__ asum) {
    if (*flag) attn_body<float, true>((const float*)x, wbf, xbf, attn_g, asum);
    else       attn_body<us, false>((const us*)x, wbf, xbf, attn_g, asum);
}

// ---------------------------------------------------------------------------
// K2 (k_vlad): per (n, 32c): vlad = a~ @ xbf^T (M=32k, N=32c, Kdim=1024p).
// A-frags direct from global a~ (L2-hot); B = xbf pure uint4 copy -> LDS,
// register-prefetch pipeline. Epilogue: -asum*cent, fp32 store, ssq atomics.
// grid 512, block 256.
// ---------------------------------------------------------------------------
template <typename T>
__device__ __forceinline__ void vlad_body(const us* __restrict__ xsrc,
                                          const us* __restrict__ attn_g,
                                          const T* __restrict__ cent,
                                          const float* __restrict__ asum,
                                          float* __restrict__ vlad,
                                          float* __restrict__ ssqnk) {
    __shared__ __align__(16) us xc[32 * 136];   // [c-local][p-chunk] pad 136
    __shared__ float asum_lds[32];
    const int b = blockIdx.x, t = threadIdx.x;
    const int n = b >> 5, cb = (b & 31) * 32;
    const int lane = t & 63, wv = t >> 6;
    const int quad = lane >> 4, l15 = lane & 15;
    const int mtk = wv >> 1, ntc = wv & 1;

    if (t < 32) asum_lds[t] = asum[n * KK + t];

    f32x4 acc = {0.f, 0.f, 0.f, 0.f};
    const size_t xb = ((size_t)n * CC + cb) * PP;
    const size_t ab = ((size_t)n * KK + mtk * 16 + l15) * PP;

    uint4 xr[2];
    #pragma unroll
    for (int s = 0; s < 2; ++s) {
        const int idx = t + 256 * s;
        xr[s] = *(const uint4*)&xsrc[xb + (size_t)(idx >> 4) * PP + (idx & 15) * 8];
    }
    for (int ch = 0; ch < 8; ++ch) {
        const int p0 = ch * 128;
        __syncthreads();
        #pragma unroll
        for (int s = 0; s < 2; ++s) {
            const int idx = t + 256 * s;
            *(uint4*)&xc[(idx >> 4) * 136 + (idx & 15) * 8] = xr[s];
        }
        __syncthreads();
        if (ch < 7) {
            #pragma unroll
            for (int s = 0; s < 2; ++s) {
                const int idx = t + 256 * s;
                xr[s] = *(const uint4*)&xsrc[xb + (size_t)(idx >> 4) * PP + p0 + 128 + (idx & 15) * 8];
            }
        }
        #pragma unroll
        for (int ks = 0; ks < 4; ++ks) {
            const bf16x8 av = *(const bf16x8*)&attn_g[ab + p0 + ks * 32 + quad * 8];
            const bf16x8 bv = *(const bf16x8*)&xc[(ntc * 16 + l15) * 136 + ks * 32 + quad * 8];
            acc = __builtin_amdgcn_mfma_f32_16x16x32_bf16(av, bv, acc, 0, 0, 0);
        }
    }
    // D: row(k)=quad*4+reg (+mtk*16), col(c)=l15 (+ntc*16)
    const int cg = cb + ntc * 16 + l15;
    #pragma unroll
    for (int reg = 0; reg < 4; ++reg) {
        const int k = mtk * 16 + quad * 4 + reg;
        const float A = asum_lds[k];
        const float v = acc[reg] - A * IO<T>::ld(&cent[k * CC + cg]);
        vlad[((size_t)n * KK + k) * CC + cg] = v;
        float s = v * v;
        s += __shfl_xor(s, 1, 64);
        s += __shfl_xor(s, 2, 64);
        s += __shfl_xor(s, 4, 64);
        s += __shfl_xor(s, 8, 64);
        if (l15 == 0) atomicAdd(&ssqnk[n * KK + k], s);
    }
}
__global__ __launch_bounds__(256) void k_vlad(const void* __restrict__ x,
                                              const us* __restrict__ xbf,
                                              const us* __restrict__ attn_g,
                                              const void* __restrict__ cent,
                                              const int* __restrict__ flag,
                                              const float* __restrict__ asum,
                                              float* __restrict__ vlad,
                                              float* __restrict__ ssqnk) {
    if (*flag) vlad_body<float>(xbf, attn_g, (const float*)cent, asum, vlad, ssqnk);
    else       vlad_body<us>((const us*)x, attn_g, (const us*)cent, asum, vlad, ssqnk);
}

// ---------------------------------------------------------------------------
// K3: per (n,k) intra rnorm; per n global rnorm (sum_k ssq_k * r_k^2).
// ---------------------------------------------------------------------------
__global__ __launch_bounds__(64) void k_factors(const float* __restrict__ ssqnk,
                                                float* __restrict__ rintra,
                                                float* __restrict__ rglob) {
    const int n = blockIdx.x, t = threadIdx.x;
    const float s = (t < KK) ? ssqnk[n * KK + t] : 0.f;
    const float r = 1.0f / fmaxf(sqrtf(s), EPSF);
    if (t < KK) rintra[n * KK + t] = r;
    float g = s * r * r;
    for (int off = 32; off > 0; off >>= 1) g += __shfl_down(g, off, 64);
    if (t == 0) rglob[n] = 1.0f / fmaxf(sqrtf(g), EPSF);
}

// ---------------------------------------------------------------------------
// K4: out = vlad * rintra * rglob. grid N*K, 256 thr (float4 per thread).
// ---------------------------------------------------------------------------
__global__ __launch_bounds__(256) void k_out(const float* __restrict__ vlad,
                                             const float* __restrict__ rintra,
                                             const float* __restrict__ rglob,
                                             const int* __restrict__ flag,
                                             void* __restrict__ out) {
    const int b = blockIdx.x, t = threadIdx.x;
    const float f = rintra[b] * rglob[b >> 5];
    const float4 v = ((const float4*)(vlad + (size_t)b * CC))[t];
    if (*flag) {
        float4 o; o.x = v.x * f; o.y = v.y * f; o.z = v.z * f; o.w = v.w * f;
        ((float4*)((float*)out + (size_t)b * CC))[t] = o;
    } else {
        ushort4 u;
        u.x = f2bf(v.x * f); u.y = f2bf(v.y * f);
        u.z = f2bf(v.z * f); u.w = f2bf(v.w * f);
        ((ushort4*)((us*)out + (size_t)b * CC))[t] = u;
    }
}

extern "C" void kernel_launch(void* const* d_in, const int* in_sizes, int n_in,
                              void* d_out, int out_size, void* d_ws, size_t ws_size,
                              hipStream_t stream) {
    const void* x    = d_in[0];
    const void* w    = d_in[1];
    const void* cent = d_in[2];

    float* ws     = (float*)d_ws;
    float* vlad   = ws;                       // 524288 f
    float* asum   = vlad + 524288;            // 512 f
    float* ssqnk  = asum + 512;               // 512 f
    float* rintra = ssqnk + 512;              // 512 f
    float* rglob  = rintra + 512;             // 16 f
    int*   flag   = (int*)(rglob + 16);       // 4 i
    us* attn_g = (us*)(flag + 4);             // 524288 us  (a~ = a*rn, bf16)
    us* xbf    = attn_g + 524288;             // 16777216 us (bf16(x) raw)
    us* wbf    = xbf + 16777216;              // 32768 us

    hipMemsetAsync(asum, 0, 2 * NB * KK * sizeof(float), stream);  // asum+ssqnk

    k_prep<<<16, 256, 0, stream>>>((const us*)x, w, flag, wbf);
    k_attn<<<NB * 32, 256, 0, stream>>>(x, wbf, flag, xbf, attn_g, asum);
    k_vlad<<<NB * 32, 256, 0, stream>>>(x, xbf, attn_g, cent, flag, asum, vlad, ssqnk);
    k_factors<<<NB, 64, 0, stream>>>(ssqnk, rintra, rglob);
    k_out<<<NB * KK, 256, 0, stream>>>(vlad, rintra, rglob, flag, d_out);
}

// Round 7
// 153.720 us; speedup vs baseline: 1.3136x; 1.1214x over previous
//
#include <hip/hip_runtime.h>

// NetVLAD: N=16, C=1024, P=1024, K=32.
// k_prep (detect + W->bf16) -> k_attn (W staged ONCE in LDS; fused rnorm +
// logits MFMA + softmax; writes a~=a*rn bf16, asum fp32, xbf) -> k_vlad
// (a~ staged ONCE in LDS; pure-copy MFMA) -> factors -> out.
#define NB   16
#define CC   1024
#define PP   1024
#define KK   32
#define EPSF 1e-12f
#define WPAD 1032   // row stride (elems) for 32x1024 LDS matrices: 2064B = free 2-way

typedef __attribute__((ext_vector_type(8))) short  bf16x8;
typedef __attribute__((ext_vector_type(4))) float  f32x4;
typedef unsigned short us;

__device__ __forceinline__ float bf2f(us u) {
    union { unsigned int i; float f; } v; v.i = ((unsigned int)u) << 16; return v.f;
}
__device__ __forceinline__ us f2bf(float f) {
    union { float f; unsigned int i; } v; v.f = f;
    return (us)((v.i + 0x7fffu + ((v.i >> 16) & 1u)) >> 16);  // RNE
}

template <typename T> struct IO;
template <> struct IO<float> {
    static __device__ __forceinline__ float  ld (const float* p) { return *p; }
    static __device__ __forceinline__ float4 ld4(const float* p) { return *(const float4*)p; }
};
template <> struct IO<us> {
    static __device__ __forceinline__ float  ld (const us* p) { return bf2f(*p); }
    static __device__ __forceinline__ float4 ld4(const us* p) {
        const ushort4 u = *(const ushort4*)p;
        return make_float4(bf2f(u.x), bf2f(u.y), bf2f(u.z), bf2f(u.w));
    }
};

// ---------------------------------------------------------------------------
// K0 (k_prep): grid 16. Per-block dtype detect (order-free); block 0 publishes
// flag; every block converts/copies its W slice to bf16.
// ---------------------------------------------------------------------------
__global__ __launch_bounds__(256) void k_prep(const us* __restrict__ xu,
                                              const void* __restrict__ w,
                                              int* __restrict__ flag,
                                              us* __restrict__ wbf) {
    __shared__ int s;
    const int b = blockIdx.x, t = threadIdx.x;
    if (t == 0) s = 0;
    __syncthreads();
    int bad = 0;
    for (int i = t; i < 4096; i += 256)
        if (((xu[i] >> 7) & 0xFFu) > 0x9Fu) bad = 1;
    if (bad) atomicOr(&s, 1);
    __syncthreads();
    const int f = s;
    if (b == 0 && t == 0) flag[0] = f;
    const int base = b * 2048 + t * 8;
    if (f) {
        const float* wf = (const float*)w;
        const float4 v0 = *(const float4*)(wf + base);
        const float4 v1 = *(const float4*)(wf + base + 4);
        ushort4 u0, u1;
        u0.x = f2bf(v0.x); u0.y = f2bf(v0.y); u0.z = f2bf(v0.z); u0.w = f2bf(v0.w);
        u1.x = f2bf(v1.x); u1.y = f2bf(v1.y); u1.z = f2bf(v1.z); u1.w = f2bf(v1.w);
        *(ushort4*)&wbf[base]     = u0;
        *(ushort4*)&wbf[base + 4] = u1;
    } else {
        *(uint4*)&wbf[base] = *(const uint4*)((const us*)w + base);
    }
}

// ---------------------------------------------------------------------------
// K1 (k_attn): per (n, 32px). W staged once into LDS (pad-8 rows). K-loop:
// consume prefetched x regs (sumsq + cvt + LDS transpose scatter + xbf),
// prefetch next chunk, MFMA from LDS only. Epilogue: rnorm, softmax,
// a~ = a*rn bf16 + asum fp32. grid 512, block 256.
// LDS: wlds 66048 + xt 8704 (reused as red+lg) + 256 = ~75 KB -> 2 blocks/CU.
// ---------------------------------------------------------------------------
template <typename T, bool WRITE_XBF>
__device__ __forceinline__ void attn_body(const T* __restrict__ x,
                                          const us* __restrict__ wbf,
                                          us* __restrict__ xbf,
                                          us* __restrict__ attn_g,
                                          float* __restrict__ asum) {
    __shared__ __align__(16) us wlds[32 * WPAD];     // [k][c] pad
    __shared__ __align__(16) us xt[32 * 136];        // [px][c-chunk]; reused
    __shared__ float inv_lds[32];
    __shared__ float rn_lds[32];
    float* red = (float*)xt;                         // 32*33 f (post-loop)
    float* lg  = (float*)xt + 32 * 33;               // 32*33 f (post-loop)

    const int b = blockIdx.x, t = threadIdx.x;
    const int n = b >> 5, pbase = (b & 31) * 32;
    const int lane = t & 63, wv = t >> 6;
    const int quad = lane >> 4, l15 = lane & 15;
    const int mt = wv >> 1, ntk = wv & 1;
    const int a = t & 7, crow = t >> 3, pxg = 4 * a;
    const size_t xb = (size_t)n * CC * PP + pbase;

    // stage whole W: 4096 uint4 units
    #pragma unroll
    for (int i = 0; i < 16; ++i) {
        const int u = t + 256 * i;
        const int row = u >> 7, col8 = (u & 127) * 8;
        *(uint4*)&wlds[row * WPAD + col8] = *(const uint4*)&wbf[row * 1024 + col8];
    }

    float ss0 = 0.f, ss1 = 0.f, ss2 = 0.f, ss3 = 0.f;
    f32x4 acc = {0.f, 0.f, 0.f, 0.f};

    // prefetch chunk 0
    float4 xr[4];
    #pragma unroll
    for (int ps = 0; ps < 4; ++ps)
        xr[ps] = IO<T>::ld4(x + xb + (size_t)(crow + 32 * ps) * PP + pxg);

    for (int ch = 0; ch < 8; ++ch) {
        const int c0 = ch * 128;
        __syncthreads();   // (ch==0: also covers W stage)
        #pragma unroll
        for (int ps = 0; ps < 4; ++ps) {
            const float4 v = xr[ps];
            ss0 += v.x * v.x; ss1 += v.y * v.y; ss2 += v.z * v.z; ss3 += v.w * v.w;
            ushort4 u;
            u.x = f2bf(v.x); u.y = f2bf(v.y); u.z = f2bf(v.z); u.w = f2bf(v.w);
            const int cl = crow + 32 * ps;
            xt[(pxg + 0) * 136 + cl] = u.x;
            xt[(pxg + 1) * 136 + cl] = u.y;
            xt[(pxg + 2) * 136 + cl] = u.z;
            xt[(pxg + 3) * 136 + cl] = u.w;
            if (WRITE_XBF)
                *(ushort4*)&xbf[(size_t)(n * CC + c0 + cl) * PP + pbase + pxg] = u;
        }
        __syncthreads();
        if (ch < 7) {
            const int c0n = c0 + 128;
            #pragma unroll
            for (int ps = 0; ps < 4; ++ps)
                xr[ps] = IO<T>::ld4(x + xb + (size_t)(c0n + crow + 32 * ps) * PP + pxg);
        }
        #pragma unroll
        for (int ks = 0; ks < 4; ++ks) {
            const bf16x8 av = *(const bf16x8*)&xt[(mt * 16 + l15) * 136 + ks * 32 + quad * 8];
            const bf16x8 bv = *(const bf16x8*)&wlds[(ntk * 16 + l15) * WPAD + c0 + ks * 32 + quad * 8];
            acc = __builtin_amdgcn_mfma_f32_16x16x32_bf16(av, bv, acc, 0, 0, 0);
        }
    }
    __syncthreads();   // xt now free -> becomes red/lg
    red[crow * 33 + pxg + 0] = ss0;
    red[crow * 33 + pxg + 1] = ss1;
    red[crow * 33 + pxg + 2] = ss2;
    red[crow * 33 + pxg + 3] = ss3;
    __syncthreads();
    if (t < 32) {
        float s = 0.f;
        #pragma unroll
        for (int g = 0; g < 32; ++g) s += red[g * 33 + t];
        rn_lds[t] = 1.0f / fmaxf(sqrtf(s), EPSF);
    }
    __syncthreads();
    #pragma unroll
    for (int reg = 0; reg < 4; ++reg) {
        const int px = mt * 16 + quad * 4 + reg;
        lg[px * 33 + ntk * 16 + l15] = acc[reg] * rn_lds[px];
    }
    __syncthreads();
    if (t < 32) {
        float m = -1e30f;
        #pragma unroll
        for (int k = 0; k < KK; ++k) m = fmaxf(m, lg[t * 33 + k]);
        float s = 0.f;
        #pragma unroll
        for (int k = 0; k < KK; ++k) {
            const float e = expf(lg[t * 33 + k] - m);
            lg[t * 33 + k] = e;
            s += e;
        }
        inv_lds[t] = 1.0f / s;
    }
    __syncthreads();
    {
        const int k = t >> 3, ps2 = (t & 7) * 4;
        ushort4 u;
        float sum = 0.f;
        #pragma unroll
        for (int j = 0; j < 4; ++j) {
            const int px = ps2 + j;
            const float e = lg[px * 33 + k] * inv_lds[px];   // a (fp32)
            sum += e;
            ((us*)&u)[j] = f2bf(e * rn_lds[px]);             // a~ bf16
        }
        *(ushort4*)&attn_g[((size_t)n * KK + k) * PP + pbase + ps2] = u;
        sum += __shfl_down(sum, 1, 64);
        sum += __shfl_down(sum, 2, 64);
        sum += __shfl_down(sum, 4, 64);
        if ((t & 7) == 0) atomicAdd(&asum[n * KK + k], sum);
    }
}
__global__ __launch_bounds__(256) void k_attn(const void* __restrict__ x,
                                              const us* __restrict__ wbf,
                                              const int* __restrict__ flag,
                                              us* __restrict__ xbf,
                                              us* __restrict__ attn_g,
                                              float* __restrict__ asum) {
    if (*flag) attn_body<float, true>((const float*)x, wbf, xbf, attn_g, asum);
    else       attn_body<us, false>((const us*)x, wbf, xbf, attn_g, asum);
}

// ---------------------------------------------------------------------------
// K2 (k_vlad): per (n, 32c). a~ staged once into LDS (pad-8 rows). K-loop:
// stage xbf chunk (pure uint4 copies, reg-prefetched), MFMA from LDS only.
// Epilogue: -asum*cent, fp32 store, ssq atomics. grid 512, block 256.
// LDS: alds 66048 + xc 8704 + 128 = ~75 KB -> 2 blocks/CU.
// ---------------------------------------------------------------------------
template <typename T>
__device__ __forceinline__ void vlad_body(const us* __restrict__ xsrc,
                                          const us* __restrict__ attn_g,
                                          const T* __restrict__ cent,
                                          const float* __restrict__ asum,
                                          float* __restrict__ vlad,
                                          float* __restrict__ ssqnk) {
    __shared__ __align__(16) us alds[32 * WPAD];    // [k][p] pad
    __shared__ __align__(16) us xc[32 * 136];       // [c-local][p-chunk]
    __shared__ float asum_lds[32];
    const int b = blockIdx.x, t = threadIdx.x;
    const int n = b >> 5, cb = (b & 31) * 32;
    const int lane = t & 63, wv = t >> 6;
    const int quad = lane >> 4, l15 = lane & 15;
    const int mtk = wv >> 1, ntc = wv & 1;

    if (t < 32) asum_lds[t] = asum[n * KK + t];

    // stage whole a~: 4096 uint4 units
    #pragma unroll
    for (int i = 0; i < 16; ++i) {
        const int u = t + 256 * i;
        const int row = u >> 7, col8 = (u & 127) * 8;
        *(uint4*)&alds[row * WPAD + col8] =
            *(const uint4*)&attn_g[((size_t)n * KK + row) * PP + col8];
    }

    f32x4 acc = {0.f, 0.f, 0.f, 0.f};
    const size_t xb = ((size_t)n * CC + cb) * PP;

    uint4 xr[2];
    #pragma unroll
    for (int s = 0; s < 2; ++s) {
        const int idx = t + 256 * s;
        xr[s] = *(const uint4*)&xsrc[xb + (size_t)(idx >> 4) * PP + (idx & 15) * 8];
    }
    for (int ch = 0; ch < 8; ++ch) {
        const int p0 = ch * 128;
        __syncthreads();   // (ch==0: also covers a~ stage)
        #pragma unroll
        for (int s = 0; s < 2; ++s) {
            const int idx = t + 256 * s;
            *(uint4*)&xc[(idx >> 4) * 136 + (idx & 15) * 8] = xr[s];
        }
        __syncthreads();
        if (ch < 7) {
            #pragma unroll
            for (int s = 0; s < 2; ++s) {
                const int idx = t + 256 * s;
                xr[s] = *(const uint4*)&xsrc[xb + (size_t)(idx >> 4) * PP + p0 + 128 + (idx & 15) * 8];
            }
        }
        #pragma unroll
        for (int ks = 0; ks < 4; ++ks) {
            const bf16x8 av = *(const bf16x8*)&alds[(mtk * 16 + l15) * WPAD + p0 + ks * 32 + quad * 8];
            const bf16x8 bv = *(const bf16x8*)&xc[(ntc * 16 + l15) * 136 + ks * 32 + quad * 8];
            acc = __builtin_amdgcn_mfma_f32_16x16x32_bf16(av, bv, acc, 0, 0, 0);
        }
    }
    // D: row(k)=quad*4+reg (+mtk*16), col(c)=l15 (+ntc*16)
    const int cg = cb + ntc * 16 + l15;
    #pragma unroll
    for (int reg = 0; reg < 4; ++reg) {
        const int k = mtk * 16 + quad * 4 + reg;
        const float A = asum_lds[k];
        const float v = acc[reg] - A * IO<T>::ld(&cent[k * CC + cg]);
        vlad[((size_t)n * KK + k) * CC + cg] = v;
        float s = v * v;
        s += __shfl_xor(s, 1, 64);
        s += __shfl_xor(s, 2, 64);
        s += __shfl_xor(s, 4, 64);
        s += __shfl_xor(s, 8, 64);
        if (l15 == 0) atomicAdd(&ssqnk[n * KK + k], s);
    }
}
__global__ __launch_bounds__(256) void k_vlad(const void* __restrict__ x,
                                              const us* __restrict__ xbf,
                                              const us* __restrict__ attn_g,
                                              const void* __restrict__ cent,
                                              const int* __restrict__ flag,
                                              const float* __restrict__ asum,
                                              float* __restrict__ vlad,
                                              float* __restrict__ ssqnk) {
    if (*flag) vlad_body<float>(xbf, attn_g, (const float*)cent, asum, vlad, ssqnk);
    else       vlad_body<us>((const us*)x, attn_g, (const us*)cent, asum, vlad, ssqnk);
}

// ---------------------------------------------------------------------------
// K3: per (n,k) intra rnorm; per n global rnorm (sum_k ssq_k * r_k^2).
// ---------------------------------------------------------------------------
__global__ __launch_bounds__(64) void k_factors(const float* __restrict__ ssqnk,
                                                float* __restrict__ rintra,
                                                float* __restrict__ rglob) {
    const int n = blockIdx.x, t = threadIdx.x;
    const float s = (t < KK) ? ssqnk[n * KK + t] : 0.f;
    const float r = 1.0f / fmaxf(sqrtf(s), EPSF);
    if (t < KK) rintra[n * KK + t] = r;
    float g = s * r * r;
    for (int off = 32; off > 0; off >>= 1) g += __shfl_down(g, off, 64);
    if (t == 0) rglob[n] = 1.0f / fmaxf(sqrtf(g), EPSF);
}

// ---------------------------------------------------------------------------
// K4: out = vlad * rintra * rglob. grid N*K, 256 thr (float4 per thread).
// ---------------------------------------------------------------------------
__global__ __launch_bounds__(256) void k_out(const float* __restrict__ vlad,
                                             const float* __restrict__ rintra,
                                             const float* __restrict__ rglob,
                                             const int* __restrict__ flag,
                                             void* __restrict__ out) {
    const int b = blockIdx.x, t = threadIdx.x;
    const float f = rintra[b] * rglob[b >> 5];
    const float4 v = ((const float4*)(vlad + (size_t)b * CC))[t];
    if (*flag) {
        float4 o; o.x = v.x * f; o.y = v.y * f; o.z = v.z * f; o.w = v.w * f;
        ((float4*)((float*)out + (size_t)b * CC))[t] = o;
    } else {
        ushort4 u;
        u.x = f2bf(v.x * f); u.y = f2bf(v.y * f);
        u.z = f2bf(v.z * f); u.w = f2bf(v.w * f);
        ((ushort4*)((us*)out + (size_t)b * CC))[t] = u;
    }
}

extern "C" void kernel_launch(void* const* d_in, const int* in_sizes, int n_in,
                              void* d_out, int out_size, void* d_ws, size_t ws_size,
                              hipStream_t stream) {
    const void* x    = d_in[0];
    const void* w    = d_in[1];
    const void* cent = d_in[2];

    float* ws     = (float*)d_ws;
    float* vlad   = ws;                       // 524288 f
    float* asum   = vlad + 524288;            // 512 f
    float* ssqnk  = asum + 512;               // 512 f
    float* rintra = ssqnk + 512;              // 512 f
    float* rglob  = rintra + 512;             // 16 f
    int*   flag   = (int*)(rglob + 16);       // 4 i
    us* attn_g = (us*)(flag + 4);             // 524288 us  (a~ = a*rn, bf16)
    us* xbf    = attn_g + 524288;             // 16777216 us (bf16(x) raw)
    us* wbf    = xbf + 16777216;              // 32768 us

    hipMemsetAsync(asum, 0, 2 * NB * KK * sizeof(float), stream);  // asum+ssqnk

    k_prep<<<16, 256, 0, stream>>>((const us*)x, w, flag, wbf);
    k_attn<<<NB * 32, 256, 0, stream>>>(x, wbf, flag, xbf, attn_g, asum);
    k_vlad<<<NB * 32, 256, 0, stream>>>(x, xbf, attn_g, cent, flag, asum, vlad, ssqnk);
    k_factors<<<NB, 64, 0, stream>>>(ssqnk, rintra, rglob);
    k_out<<<NB * KK, 256, 0, stream>>>(vlad, rintra, rglob, flag, d_out);
}